// Round 1
// baseline (379.787 us; speedup 1.0000x reference)
//
#include <hip/hip_runtime.h>
#include <math.h>

#define N_NODES  50000
#define N_EDGES  800000
#define IN_F     128
#define HID_F    64
#define OUT_F    32
#define N_GRAPHS 128

// ---------------------------------------------------------------------------
// K1: deg[i] = 1.0f  (self-loop weight folded into init)
__global__ __launch_bounds__(256) void init_deg_kernel(float* __restrict__ deg) {
    int i = blockIdx.x * 256 + threadIdx.x;
    if (i < N_NODES) deg[i] = 1.0f;
}

// K2: deg[dst[e]] += ew[e]
__global__ __launch_bounds__(256) void degree_kernel(const int* __restrict__ dst,
                                                     const float* __restrict__ ew,
                                                     float* __restrict__ deg) {
    int e = blockIdx.x * 256 + threadIdx.x;
    if (e < N_EDGES) atomicAdd(&deg[dst[e]], ew[e]);
}

// K3: deg -> dinv = 1/sqrt(deg)   (deg >= 1 always, no zero guard needed,
//     but keep the reference's where(deg>0) semantics anyway)
__global__ __launch_bounds__(256) void rsqrt_kernel(float* __restrict__ deg) {
    int i = blockIdx.x * 256 + threadIdx.x;
    if (i < N_NODES) {
        float d = deg[i];
        deg[i] = (d > 0.0f) ? (1.0f / sqrtf(d)) : 0.0f;
    }
}

// K4: norm[e] = dinv[src]*ew*dinv[dst]  (coalesced precompute so the wide
//     scatter kernel doesn't redo the dinv gathers 64x per edge)
__global__ __launch_bounds__(256) void norm_kernel(const int* __restrict__ src,
                                                   const int* __restrict__ dst,
                                                   const float* __restrict__ ew,
                                                   const float* __restrict__ dinv,
                                                   float* __restrict__ norm) {
    int e = blockIdx.x * 256 + threadIdx.x;
    if (e < N_EDGES) norm[e] = dinv[src[e]] * ew[e] * dinv[dst[e]];
}

// K5: h = x @ W   [50000x128]@[128x64] f32, W staged in LDS (32 KB).
// Block = 256 threads -> 64 rows/block, 4 threads per row x 16 cols each.
__global__ __launch_bounds__(256) void gemm_kernel(const float* __restrict__ x,
                                                   const float* __restrict__ W,
                                                   float* __restrict__ h) {
    __shared__ float Ws[IN_F][HID_F];
    int tid = threadIdx.x;
    for (int i = tid * 4; i < IN_F * HID_F; i += 256 * 4) {
        *(float4*)&((float*)Ws)[i] = *(const float4*)&W[i];
    }
    __syncthreads();

    int row = blockIdx.x * 64 + (tid >> 2);
    int c0  = (tid & 3) * 16;
    if (row >= N_NODES) return;

    float acc[16];
#pragma unroll
    for (int j = 0; j < 16; ++j) acc[j] = 0.0f;

    const float* xr = x + (size_t)row * IN_F;
    for (int k = 0; k < IN_F; k += 4) {
        float4 xv = *(const float4*)&xr[k];
#pragma unroll
        for (int j = 0; j < 16; ++j) {
            acc[j] += xv.x * Ws[k + 0][c0 + j];
            acc[j] += xv.y * Ws[k + 1][c0 + j];
            acc[j] += xv.z * Ws[k + 2][c0 + j];
            acc[j] += xv.w * Ws[k + 3][c0 + j];
        }
    }
    float* hr = h + (size_t)row * HID_F + c0;
#pragma unroll
    for (int j = 0; j < 16; j += 4) {
        *(float4*)&hr[j] = make_float4(acc[j], acc[j + 1], acc[j + 2], acc[j + 3]);
    }
}

// K6: scatter-add messages: out[dst] += h[src]*norm.  One wave per edge,
// lane = feature. 4 edges per 256-thread block.
__global__ __launch_bounds__(256) void scatter_kernel(const int* __restrict__ src,
                                                      const int* __restrict__ dst,
                                                      const float* __restrict__ norm,
                                                      const float* __restrict__ h,
                                                      float* __restrict__ out) {
    int e = blockIdx.x * 4 + (threadIdx.x >> 6);
    if (e >= N_EDGES) return;
    int f = threadIdx.x & 63;
    int s = src[e];
    int d = dst[e];
    float v = h[(size_t)s * HID_F + f] * norm[e];
    atomicAdd(&out[(size_t)d * HID_F + f], v);
}

// K7: out = tanh(out + h*dinv^2 + b)   (self-loop message + bias + activation)
__global__ __launch_bounds__(256) void finalize_kernel(const float* __restrict__ h,
                                                       const float* __restrict__ dinv,
                                                       const float* __restrict__ b,
                                                       float* __restrict__ out) {
    int i = blockIdx.x * 256 + threadIdx.x;
    if (i >= N_NODES * HID_F) return;
    int n = i >> 6;   // node
    int f = i & 63;   // feature
    float di = dinv[n];
    float v  = out[i] + h[i] * di * di + b[f];
    out[i] = tanhf(v);
}

// K8: graph boundaries via binary search over sorted batch.
// bounds[g] = first index with batch[i] >= g, g in [0,128]; bounds[128]=N.
__global__ void bounds_kernel(const int* __restrict__ batch, int* __restrict__ bounds) {
    int g = threadIdx.x;
    if (g > N_GRAPHS) return;
    int lo = 0, hi = N_NODES;
    while (lo < hi) {
        int m = (lo + hi) >> 1;
        if (batch[m] < g) lo = m + 1; else hi = m;
    }
    bounds[g] = lo;
}

// K9: per-graph mean-pool + [64->32] GEMM + tanh. One block per graph,
// 4 waves sum interleaved node ranges, LDS-reduce, then 32 threads do the dot.
__global__ __launch_bounds__(256) void pool_kernel(const float* __restrict__ ne,
                                                   const int* __restrict__ bounds,
                                                   const float* __restrict__ W1,
                                                   const float* __restrict__ b1,
                                                   float* __restrict__ gout) {
    __shared__ float part[4][HID_F];
    __shared__ float mean_s[HID_F];
    int g  = blockIdx.x;
    int f  = threadIdx.x & 63;
    int w  = threadIdx.x >> 6;
    int lo = bounds[g], hi = bounds[g + 1];

    float s = 0.0f;
    for (int i = lo + w; i < hi; i += 4) s += ne[(size_t)i * HID_F + f];
    part[w][f] = s;
    __syncthreads();

    if (w == 0) {
        float m   = part[0][f] + part[1][f] + part[2][f] + part[3][f];
        float cnt = (float)(hi - lo);
        mean_s[f] = m / fmaxf(cnt, 1.0f);
    }
    __syncthreads();

    int o = threadIdx.x;
    if (o < OUT_F) {
        float acc = b1[o];
        for (int k = 0; k < HID_F; ++k) acc += mean_s[k] * W1[k * OUT_F + o];
        gout[(size_t)g * OUT_F + o] = tanhf(acc);
    }
}

extern "C" void kernel_launch(void* const* d_in, const int* in_sizes, int n_in,
                              void* d_out, int out_size, void* d_ws, size_t ws_size,
                              hipStream_t stream) {
    const float* x   = (const float*)d_in[0];
    const int*   ei  = (const int*)d_in[1];          // [2][E]: src row then dst row
    const float* ew  = (const float*)d_in[2];
    const int*   bat = (const int*)d_in[3];
    // d_in[4] = num_graphs (constant 128, hardcoded)
    const float* W   = (const float*)d_in[5];
    const float* b   = (const float*)d_in[6];
    const float* W1  = (const float*)d_in[7];
    const float* b1  = (const float*)d_in[8];

    const int* src = ei;
    const int* dst = ei + N_EDGES;

    // d_out layout: [0,4096) graph embeddings, [4096, 4096+3200000) node embeddings
    float* gout = (float*)d_out;
    float* nout = (float*)d_out + (size_t)N_GRAPHS * OUT_F;

    // Workspace layout (floats): dinv[50000] | h[3.2M] | norm[800k] | bounds[129]i
    float* ws_f   = (float*)d_ws;
    float* dinv   = ws_f;                       // 50000
    float* h      = ws_f + 50000;               // 3,200,000
    float* norm   = ws_f + 3250000;             // 800,000
    int*   bounds = (int*)(ws_f + 4050000);     // 129

    // zero the node-embedding accumulator region of d_out
    hipMemsetAsync(nout, 0, (size_t)N_NODES * HID_F * sizeof(float), stream);

    init_deg_kernel<<<(N_NODES + 255) / 256, 256, 0, stream>>>(dinv);
    degree_kernel<<<(N_EDGES + 255) / 256, 256, 0, stream>>>(dst, ew, dinv);
    rsqrt_kernel<<<(N_NODES + 255) / 256, 256, 0, stream>>>(dinv);
    norm_kernel<<<(N_EDGES + 255) / 256, 256, 0, stream>>>(src, dst, ew, dinv, norm);

    gemm_kernel<<<(N_NODES + 63) / 64, 256, 0, stream>>>(x, W, h);

    scatter_kernel<<<(N_EDGES + 3) / 4, 256, 0, stream>>>(src, dst, norm, h, nout);

    finalize_kernel<<<(N_NODES * HID_F + 255) / 256, 256, 0, stream>>>(h, dinv, b, nout);

    bounds_kernel<<<1, 256, 0, stream>>>(bat, bounds);

    pool_kernel<<<N_GRAPHS, 256, 0, stream>>>(nout, bounds, W1, b1, gout);
}